// Round 8
// baseline (134.353 us; speedup 1.0000x reference)
//
#include <hip/hip_runtime.h>
#include <cfloat>

// Emu3 VQ-VAE vector quantizer argmin (exact-rounding match to numpy ref):
//   x [9216,4] f32 (channels-last gather from [1,4,4,48,48])
//   e [32768,4] f32
//   out[n] = argmin_k fl( fl(x2+e2) - 2*fl(dot) ), first-min tie semantics.
//
// Round 13 — instruction diet, part 2 (addressing + load count):
//  - R12 (-6%) + R8 (-5%) vs flat occupancy/prefetch/SMEM rounds: the only
//    working lever is instructions removed from the per-CU stream.
//  - Lane remap: each lane owns 4 CONSECUTIVE entries (tid*4+{0..3}):
//      * cb loads -> saddr + voffset(tid*64) + imm{0,16,32,48}: ONE address
//        calc per 4 entries (SGPR base stepped on SALU, free) vs 16 VALU.
//      * e2 for the group = one aligned dwordx4 (4 loads -> 1).
//      * k0..k3 are row-independent VGPRs computed once per group -> pair
//        winner cndmask has VGPR operands (no SGPR-pair movs).
//  - Update: validated min3-pair scheme x2 (2.5 ops/eval). Tie order exact:
//    within-pair (d0<=d1) picks lower k; pair2 strict-< vs updated best
//    keeps pair1; chunks ascend; butterfly is lexicographic (d,k).
//  - Distance chain bitwise unchanged (mul,3xfma,fadd,fma). absmax must be 0.
//  - Static ~9.3 -> ~8.9 instr/eval + SALU/mov clutter removed.

#define ROWS  12
#define BLOCK 512
#define WAVES (BLOCK / 64)
#define NROWS 9216
#define NK    32768
#define GE    4                    // consecutive entries per lane per group
#define CHUNK (BLOCK * GE)         // 2048 entries per chunk

__device__ __forceinline__ float rlf(float v) {
    return __builtin_bit_cast(float,
        __builtin_amdgcn_readfirstlane(__builtin_bit_cast(int, v)));
}

__global__ __launch_bounds__(256)
void vq_prep(const float4* __restrict__ cb, float* __restrict__ e2t)
{
    int k = blockIdx.x * 256 + threadIdx.x;   // 32768 threads
    float4 e = cb[k];
    e2t[k] = __fadd_rn(__fadd_rn(__fadd_rn(__fmul_rn(e.x, e.x),
                                           __fmul_rn(e.y, e.y)),
                                 __fmul_rn(e.z, e.z)),
                       __fmul_rn(e.w, e.w));
}

__global__ __launch_bounds__(BLOCK)
__attribute__((amdgpu_waves_per_eu(3, 4)))
void vq_argmin_kernel(const float* __restrict__ hs,
                      const float4* __restrict__ cb,
                      const float4* __restrict__ e2t4,
                      int* __restrict__ out)
{
    __shared__ float sRD[WAVES * ROWS];
    __shared__ int   sRI[WAVES * ROWS];

    const int tid = threadIdx.x;
    const int rowbase = blockIdx.x * ROWS;

    // Block-uniform x components -> readfirstlane into SGPRs.
    float sx0[ROWS], sx1[ROWS], sx2[ROWS], sx3[ROWS], sq[ROWS];
    float best[ROWS];
    int   bidx[ROWS];                // full codebook index of current best

    #pragma unroll
    for (int r = 0; r < ROWS; ++r) {
        int n = rowbase + r;
        int t = n / 2304;                 // 2304 = 48*48
        int rem = n - t * 2304;
        const float* ptr = hs + t * 9216 + rem;   // + c*2304 per channel
        float a0 = ptr[0], a1 = ptr[2304], a2 = ptr[4608], a3 = ptr[6912];
        float q = __fadd_rn(__fadd_rn(__fadd_rn(__fmul_rn(a0, a0),
                                                __fmul_rn(a1, a1)),
                                      __fmul_rn(a2, a2)),
                            __fmul_rn(a3, a3));
        sx0[r] = rlf(a0); sx1[r] = rlf(a1);
        sx2[r] = rlf(a2); sx3[r] = rlf(a3);
        sq[r]  = rlf(q);
        best[r] = FLT_MAX; bidx[r] = 0;
    }

    float4 eA[GE], eB[GE];
    float4 qA, qB;                    // e2 for the 4 entries, one dwordx4

    const int lane4 = tid * GE;       // element offset of this lane's group

    auto load_group = [&](float4* e, float4& q, int tb) {
        const float4* cp = cb + (tb + lane4);     // saddr(tb)+voffset(lane4)
        e[0] = cp[0]; e[1] = cp[1]; e[2] = cp[2]; e[3] = cp[3];
        q = e2t4[(tb >> 2) + tid];                // one aligned 16B load
    };
    auto compute_group = [&](const float4* e, const float4& q, int tb) {
        const int k0 = tb + lane4;    // row-independent, amortized over ROWS
        const int k1 = k0 + 1, k2 = k0 + 2, k3 = k0 + 3;
        #pragma unroll
        for (int r = 0; r < ROWS; ++r) {
            float d0, d1, d2, d3;
            {
                float dt = __fmul_rn(sx0[r], e[0].x);
                dt = __fmaf_rn(sx1[r], e[0].y, dt);
                dt = __fmaf_rn(sx2[r], e[0].z, dt);
                dt = __fmaf_rn(sx3[r], e[0].w, dt);
                d0 = __fmaf_rn(dt, -2.0f, __fadd_rn(sq[r], q.x));
            }
            {
                float dt = __fmul_rn(sx0[r], e[1].x);
                dt = __fmaf_rn(sx1[r], e[1].y, dt);
                dt = __fmaf_rn(sx2[r], e[1].z, dt);
                dt = __fmaf_rn(sx3[r], e[1].w, dt);
                d1 = __fmaf_rn(dt, -2.0f, __fadd_rn(sq[r], q.y));
            }
            {
                float dt = __fmul_rn(sx0[r], e[2].x);
                dt = __fmaf_rn(sx1[r], e[2].y, dt);
                dt = __fmaf_rn(sx2[r], e[2].z, dt);
                dt = __fmaf_rn(sx3[r], e[2].w, dt);
                d2 = __fmaf_rn(dt, -2.0f, __fadd_rn(sq[r], q.z));
            }
            {
                float dt = __fmul_rn(sx0[r], e[3].x);
                dt = __fmaf_rn(sx1[r], e[3].y, dt);
                dt = __fmaf_rn(sx2[r], e[3].z, dt);
                dt = __fmaf_rn(sx3[r], e[3].w, dt);
                d3 = __fmaf_rn(dt, -2.0f, __fadd_rn(sq[r], q.w));
            }
            // pair 1: entries k0,k1  (min3 + winner-select, first-min exact)
            {
                float nb = fminf(fminf(best[r], d0), d1);
                int   w  = (d0 <= d1) ? k0 : k1;
                if (nb < best[r]) bidx[r] = w;
                best[r] = nb;
            }
            // pair 2: entries k2,k3 (strict < vs updated best keeps pair 1)
            {
                float nb = fminf(fminf(best[r], d2), d3);
                int   w  = (d2 <= d3) ? k2 : k3;
                if (nb < best[r]) bidx[r] = w;
                best[r] = nb;
            }
        }
    };

    // ---- ping-pong K loop: load one group while computing the other
    load_group(eA, qA, 0);
    for (int tb = 0; tb < NK; tb += 2 * CHUNK) {      // 8 iterations
        load_group(eB, qB, tb + CHUNK);
        compute_group(eA, qA, tb);
        int nb2 = tb + 2 * CHUNK < NK ? tb + 2 * CHUNK : 0;  // last: dummy
        load_group(eA, qA, nb2);
        compute_group(eB, qB, tb + CHUNK);
    }

    // ---- wave-level lexicographic (dist, idx) butterfly reduction
    #pragma unroll
    for (int r = 0; r < ROWS; ++r) {
        float d = best[r]; int i = bidx[r];
        #pragma unroll
        for (int off = 32; off >= 1; off >>= 1) {
            float d2 = __shfl_xor(d, off, 64);
            int   i2 = __shfl_xor(i, off, 64);
            if (d2 < d || (d2 == d && i2 < i)) { d = d2; i = i2; }
        }
        best[r] = d; bidx[r] = i;
    }

    int wave = tid >> 6;
    if ((tid & 63) == 0) {
        #pragma unroll
        for (int r = 0; r < ROWS; ++r) {
            sRD[wave * ROWS + r] = best[r];
            sRI[wave * ROWS + r] = bidx[r];
        }
    }
    __syncthreads();

    if (tid < ROWS) {
        float d = sRD[tid]; int i = sRI[tid];
        #pragma unroll
        for (int w = 1; w < WAVES; ++w) {
            float d2 = sRD[w * ROWS + tid];
            int   i2 = sRI[w * ROWS + tid];
            if (d2 < d || (d2 == d && i2 < i)) { d = d2; i = i2; }
        }
        out[rowbase + tid] = i;
    }
}

extern "C" void kernel_launch(void* const* d_in, const int* in_sizes, int n_in,
                              void* d_out, int out_size, void* d_ws, size_t ws_size,
                              hipStream_t stream)
{
    const float*  hs = (const float*)d_in[0];    // [1,4,4,48,48]
    const float4* cb = (const float4*)d_in[1];   // [32768,4]
    int* out = (int*)d_out;                      // [9216] int32

    float* e2t = (float*)d_ws;                   // 128 KiB in workspace

    vq_prep<<<NK / 256, 256, 0, stream>>>(cb, e2t);

    dim3 grid(NROWS / ROWS), block(BLOCK);       // 768 blocks
    vq_argmin_kernel<<<grid, block, 0, stream>>>(hs, cb, (const float4*)e2t, out);
}

// Round 9
// 127.832 us; speedup vs baseline: 1.0510x; 1.0510x over previous
//
#include <hip/hip_runtime.h>
#include <cfloat>

// Emu3 VQ-VAE vector quantizer argmin (exact-rounding match to numpy ref):
//   x [9216,4] f32 (channels-last gather from [1,4,4,48,48])
//   e [32768,4] f32
//   out[n] = argmin_k fl( fl(x2+e2) - 2*fl(dot) ), first-min tie semantics.
//
// Round 14 — K-split x2: clean occupancy test, zero stream inflation:
//  - R13 post-mortem: consecutive-entry lane remap broke coalescing (64B
//    lane stride -> 4x VMEM transactions) -> 91us. Reverted to R12 hot loop.
//  - Occupancy story was NOT closed: R6 (47%) had VGPR=32 serialization,
//    R11 (83%) spilled. The intact VGPR-64 kernel never ran above ~3
//    waves/SIMD; R12's 28% VALU-idle matches all-waves-in-vmcnt-window.
//    waves_per_eu(3,4) max=4 may also have been capping residency.
//  - Change: split codebook sweep across 2 blocks/row-group (grid 1536,
//    16K entries each). Same per-eval instruction stream, same coalesced
//    loads, L2-resident codebook -> only delta is ~2x resident waves.
//  - Combine via R10-VALIDATED u64 atomicMin key bits(d)<<32|k (d ~ 4 > 0
//    on this data, absmax=0 proven in R10; u64 min == (min d, min k) ==
//    first-min tie semantics exactly).
//  - waves_per_eu(4,8): min-4 budget (<=128 VGPR) >> the 64 chosen
//    demand-driven -> codegen unchanged, max no longer caps at 4.
//  - Distance chain bitwise unchanged from R12. absmax must stay 0.

#define ROWS   12
#define BLOCK  512
#define WAVES  (BLOCK / 64)
#define NROWS  9216
#define NRG    (NROWS / ROWS)      // 768 row groups
#define KSPLIT 2
#define NK     32768
#define NSEG   (NK / KSPLIT)       // 16384 entries per segment
#define EPT    2
#define CHUNK  (BLOCK * EPT)       // 1024

__device__ __forceinline__ float rlf(float v) {
    return __builtin_bit_cast(float,
        __builtin_amdgcn_readfirstlane(__builtin_bit_cast(int, v)));
}

__global__ __launch_bounds__(256)
void vq_prep(const float4* __restrict__ cb, float* __restrict__ e2t,
             unsigned long long* __restrict__ keys)
{
    int k = blockIdx.x * 256 + threadIdx.x;   // 32768 threads
    float4 e = cb[k];
    e2t[k] = __fadd_rn(__fadd_rn(__fadd_rn(__fmul_rn(e.x, e.x),
                                           __fmul_rn(e.y, e.y)),
                                 __fmul_rn(e.z, e.z)),
                       __fmul_rn(e.w, e.w));
    if (k < NROWS) keys[k] = ~0ull;
}

__global__ __launch_bounds__(BLOCK)
__attribute__((amdgpu_waves_per_eu(4, 8)))
void vq_argmin_kernel(const float* __restrict__ hs,
                      const float4* __restrict__ cb,
                      const float* __restrict__ e2t,
                      unsigned long long* __restrict__ keys)
{
    __shared__ float sRD[WAVES * ROWS];
    __shared__ int   sRI[WAVES * ROWS];

    const int tid  = threadIdx.x;
    const int rg   = blockIdx.x % NRG;        // row group
    const int seg  = blockIdx.x / NRG;        // codebook segment
    const int rowbase = rg * ROWS;
    const int base    = seg * NSEG;

    // Block-uniform x components -> readfirstlane into SGPRs.
    float sx0[ROWS], sx1[ROWS], sx2[ROWS], sx3[ROWS], sq[ROWS];
    float best[ROWS];
    int   bidx[ROWS];   // stores chunk index m; k = m*BLOCK + tid

    #pragma unroll
    for (int r = 0; r < ROWS; ++r) {
        int n = rowbase + r;
        int t = n / 2304;                 // 2304 = 48*48
        int rem = n - t * 2304;
        const float* ptr = hs + t * 9216 + rem;   // + c*2304 per channel
        float a0 = ptr[0], a1 = ptr[2304], a2 = ptr[4608], a3 = ptr[6912];
        float q = __fadd_rn(__fadd_rn(__fadd_rn(__fmul_rn(a0, a0),
                                                __fmul_rn(a1, a1)),
                                      __fmul_rn(a2, a2)),
                            __fmul_rn(a3, a3));
        sx0[r] = rlf(a0); sx1[r] = rlf(a1);
        sx2[r] = rlf(a2); sx3[r] = rlf(a3);
        sq[r]  = rlf(q);
        best[r] = FLT_MAX; bidx[r] = 0;
    }

    float4 eA[EPT], eB[EPT];
    float  qA[EPT], qB[EPT];

    auto load_chunk = [&](float4* e, float* q, int tb) {
        #pragma unroll
        for (int j = 0; j < EPT; ++j) {
            e[j] = cb[tb + tid + j * BLOCK];
            q[j] = e2t[tb + tid + j * BLOCK];
        }
    };
    auto compute_chunk = [&](const float4* e, const float* q, int tb) {
        float4 ea = e[0], eb = e[1];
        float  qa = q[0], qb = q[1];
        int m1 = tb / BLOCK;              // uniform chunk indices
        int m2 = m1 + 1;
        #pragma unroll
        for (int r = 0; r < ROWS; ++r) {
            float dota = __fmul_rn(sx0[r], ea.x);
            dota = __fmaf_rn(sx1[r], ea.y, dota);
            dota = __fmaf_rn(sx2[r], ea.z, dota);
            dota = __fmaf_rn(sx3[r], ea.w, dota);
            float ta = __fadd_rn(sq[r], qa);
            float da = __fmaf_rn(dota, -2.0f, ta);

            float dotb = __fmul_rn(sx0[r], eb.x);
            dotb = __fmaf_rn(sx1[r], eb.y, dotb);
            dotb = __fmaf_rn(sx2[r], eb.z, dotb);
            dotb = __fmaf_rn(sx3[r], eb.w, dotb);
            float tb2 = __fadd_rn(sq[r], qb);
            float db = __fmaf_rn(dotb, -2.0f, tb2);

            // min3 pair-update: 5 VALU for 2 evals, first-min tie-exact.
            float nb = fminf(fminf(best[r], da), db);   // -> v_min3_f32
            int   w  = (da <= db) ? m1 : m2;            // pair winner (tie->m1)
            if (nb < best[r]) bidx[r] = w;              // strict < keeps earliest
            best[r] = nb;
        }
    };

    // ---- ping-pong K loop over this block's segment
    load_chunk(eA, qA, base);
    for (int tb = base; tb < base + NSEG; tb += 2 * CHUNK) {
        load_chunk(eB, qB, tb + CHUNK);
        compute_chunk(eA, qA, tb);
        int nb2 = tb + 2 * CHUNK < base + NSEG ? tb + 2 * CHUNK : base;
        load_chunk(eA, qA, nb2);                 // last iter: dummy reload
        compute_chunk(eB, qB, tb + CHUNK);
    }

    // ---- expand chunk index -> full codebook index, then reduce
    int kk[ROWS];
    #pragma unroll
    for (int r = 0; r < ROWS; ++r) kk[r] = bidx[r] * BLOCK + tid;

    // wave-level lexicographic (dist, idx) butterfly reduction
    #pragma unroll
    for (int r = 0; r < ROWS; ++r) {
        float d = best[r]; int i = kk[r];
        #pragma unroll
        for (int off = 32; off >= 1; off >>= 1) {
            float d2 = __shfl_xor(d, off, 64);
            int   i2 = __shfl_xor(i, off, 64);
            if (d2 < d || (d2 == d && i2 < i)) { d = d2; i = i2; }
        }
        best[r] = d; kk[r] = i;
    }

    int wave = tid >> 6;
    if ((tid & 63) == 0) {
        #pragma unroll
        for (int r = 0; r < ROWS; ++r) {
            sRD[wave * ROWS + r] = best[r];
            sRI[wave * ROWS + r] = kk[r];
        }
    }
    __syncthreads();

    if (tid < ROWS) {
        float d = sRD[tid]; int i = sRI[tid];
        #pragma unroll
        for (int w = 1; w < WAVES; ++w) {
            float d2 = sRD[w * ROWS + tid];
            int   i2 = sRI[w * ROWS + tid];
            if (d2 < d || (d2 == d && i2 < i)) { d = d2; i = i2; }
        }
        // d > 0 on this data -> f32 bit order == numeric order.
        // u64 min of (bits(d)<<32 | k) == (min d, then min k) == reference
        // first-min tie semantics (validated in R10, absmax=0).
        unsigned long long key =
            ((unsigned long long)__builtin_bit_cast(unsigned, d) << 32) |
            (unsigned)i;
        atomicMin(keys + rowbase + tid, key);
    }
}

__global__ __launch_bounds__(256)
void vq_extract(const unsigned long long* __restrict__ keys,
                int* __restrict__ out)
{
    int n = blockIdx.x * 256 + threadIdx.x;   // 9216 threads
    out[n] = (int)(keys[n] & 0xFFFFFFFFull);
}

extern "C" void kernel_launch(void* const* d_in, const int* in_sizes, int n_in,
                              void* d_out, int out_size, void* d_ws, size_t ws_size,
                              hipStream_t stream)
{
    const float*  hs = (const float*)d_in[0];    // [1,4,4,48,48]
    const float4* cb = (const float4*)d_in[1];   // [32768,4]
    int* out = (int*)d_out;                      // [9216] int32

    unsigned long long* keys = (unsigned long long*)d_ws;          // 72 KiB
    float* e2t = (float*)((char*)d_ws + NROWS * sizeof(unsigned long long));
                                                                   // 128 KiB

    vq_prep<<<NK / 256, 256, 0, stream>>>(cb, e2t, keys);

    dim3 grid(NRG * KSPLIT), block(BLOCK);       // 1536 blocks
    vq_argmin_kernel<<<grid, block, 0, stream>>>(hs, cb, e2t, keys);

    vq_extract<<<NROWS / 256, 256, 0, stream>>>(keys, out);
}

// Round 10
// 123.420 us; speedup vs baseline: 1.0886x; 1.0357x over previous
//
#include <hip/hip_runtime.h>
#include <cfloat>

// Emu3 VQ-VAE vector quantizer argmin (exact-rounding match to numpy ref):
//   x [9216,4] f32 (channels-last gather from [1,4,4,48,48])
//   e [32768,4] f32
//   out[n] = argmin_k fl( fl(x2+e2) - 2*fl(dot) ), first-min tie semantics.
//
// Round 15 — final op-diet + issue-arbitration hint on the R12 skeleton:
//  - Model that fits R5-R14: issue-bound on emitted stream (~10.5 VALU/eval)
//    at sustained clock ~1.8GHz, VALUBusy ~73% real; slope ~4.5us per
//    op/eval removed (R8 -5%, R12 -6% both match). Occupancy lever dead
//    (R6/R9/R11/R14); K-split dead; SMEM dead; coalescing-remap dead.
//  - Change 1: paired-permuted e2 table: prep writes e2 so each lane loads
//    its chunk's two e2 values as ONE dwordx2 (bitwise-same values,
//    coalesced): loads 4->3 per chunk, -2 addr VALU.
//  - Change 2: peeled tail (no dummy wrap reload, no per-iter wrap select).
//  - Change 3: s_setprio(1) around compute phases (T5): blocks are
//    barrier-free and phase-diverse here (unlike lockstep GEMM) -> compute-
//    phase waves win issue arbitration over load-phase waves.
//  - Distance chain + min3 pair-update bitwise identical to R12 (absmax 0).
//  - Pre-commit: flat/worse => ROOFLINE, revert to R12.

#define ROWS  12
#define BLOCK 512
#define WAVES (BLOCK / 64)
#define NROWS 9216
#define NK    32768
#define EPT   2
#define CHUNK (BLOCK * EPT)   // 1024

__device__ __forceinline__ float rlf(float v) {
    return __builtin_bit_cast(float,
        __builtin_amdgcn_readfirstlane(__builtin_bit_cast(int, v)));
}

__global__ __launch_bounds__(256)
void vq_prep(const float4* __restrict__ cb, float* __restrict__ e2p)
{
    int k = blockIdx.x * 256 + threadIdx.x;   // 32768 threads
    float4 e = cb[k];
    float q = __fadd_rn(__fadd_rn(__fadd_rn(__fmul_rn(e.x, e.x),
                                            __fmul_rn(e.y, e.y)),
                                  __fmul_rn(e.z, e.z)),
                        __fmul_rn(e.w, e.w));
    // Permuted layout: chunk c = k>>10, w = k&1023. Lane t of chunk c reads
    // float2 at (c*512 + t): .x = e2(c*1024+t), .y = e2(c*1024+512+t).
    int c = k >> 10;
    int w = k & 1023;
    int pos = c * 1024 + ((w < 512) ? (2 * w) : (2 * (w - 512) + 1));
    e2p[pos] = q;
}

__global__ __launch_bounds__(BLOCK)
__attribute__((amdgpu_waves_per_eu(3, 4)))
void vq_argmin_kernel(const float* __restrict__ hs,
                      const float4* __restrict__ cb,
                      const float2* __restrict__ e2p2,
                      int* __restrict__ out)
{
    __shared__ float sRD[WAVES * ROWS];
    __shared__ int   sRI[WAVES * ROWS];

    const int tid = threadIdx.x;
    const int rowbase = blockIdx.x * ROWS;

    // Block-uniform x components -> readfirstlane into SGPRs.
    float sx0[ROWS], sx1[ROWS], sx2[ROWS], sx3[ROWS], sq[ROWS];
    float best[ROWS];
    int   bidx[ROWS];   // stores chunk index m; k = m*BLOCK + tid

    #pragma unroll
    for (int r = 0; r < ROWS; ++r) {
        int n = rowbase + r;
        int t = n / 2304;                 // 2304 = 48*48
        int rem = n - t * 2304;
        const float* ptr = hs + t * 9216 + rem;   // + c*2304 per channel
        float a0 = ptr[0], a1 = ptr[2304], a2 = ptr[4608], a3 = ptr[6912];
        float q = __fadd_rn(__fadd_rn(__fadd_rn(__fmul_rn(a0, a0),
                                                __fmul_rn(a1, a1)),
                                      __fmul_rn(a2, a2)),
                            __fmul_rn(a3, a3));
        sx0[r] = rlf(a0); sx1[r] = rlf(a1);
        sx2[r] = rlf(a2); sx3[r] = rlf(a3);
        sq[r]  = rlf(q);
        best[r] = FLT_MAX; bidx[r] = 0;
    }

    float4 eA[EPT], eB[EPT];
    float2 qA, qB;                        // paired e2 for the two entries

    auto load_chunk = [&](float4* e, float2& q, int tb) {
        #pragma unroll
        for (int j = 0; j < EPT; ++j) e[j] = cb[tb + tid + j * BLOCK];
        q = e2p2[(tb >> 10) * 512 + tid];           // one dwordx2
    };
    auto compute_chunk = [&](const float4* e, const float2& q, int tb) {
        __builtin_amdgcn_s_setprio(1);
        float4 ea = e[0], eb = e[1];
        float  qa = q.x, qb = q.y;
        int m1 = tb / BLOCK;              // uniform chunk indices
        int m2 = m1 + 1;
        #pragma unroll
        for (int r = 0; r < ROWS; ++r) {
            float dota = __fmul_rn(sx0[r], ea.x);
            dota = __fmaf_rn(sx1[r], ea.y, dota);
            dota = __fmaf_rn(sx2[r], ea.z, dota);
            dota = __fmaf_rn(sx3[r], ea.w, dota);
            float ta = __fadd_rn(sq[r], qa);
            float da = __fmaf_rn(dota, -2.0f, ta);

            float dotb = __fmul_rn(sx0[r], eb.x);
            dotb = __fmaf_rn(sx1[r], eb.y, dotb);
            dotb = __fmaf_rn(sx2[r], eb.z, dotb);
            dotb = __fmaf_rn(sx3[r], eb.w, dotb);
            float tb2 = __fadd_rn(sq[r], qb);
            float db = __fmaf_rn(dotb, -2.0f, tb2);

            // min3 pair-update: 5 VALU for 2 evals, first-min tie-exact.
            float nb = fminf(fminf(best[r], da), db);   // -> v_min3_f32
            int   w  = (da <= db) ? m1 : m2;            // pair winner (tie->m1)
            if (nb < best[r]) bidx[r] = w;              // strict < keeps earliest
            best[r] = nb;
        }
        __builtin_amdgcn_s_setprio(0);
    };

    // ---- ping-pong K loop, peeled tail (no dummy reload)
    load_chunk(eA, qA, 0);
    int tb = 0;
    for (; tb + 2 * CHUNK < NK; tb += 2 * CHUNK) {    // 15 full iterations
        load_chunk(eB, qB, tb + CHUNK);
        compute_chunk(eA, qA, tb);
        load_chunk(eA, qA, tb + 2 * CHUNK);
        compute_chunk(eB, qB, tb + CHUNK);
    }
    load_chunk(eB, qB, tb + CHUNK);                   // final pair
    compute_chunk(eA, qA, tb);
    compute_chunk(eB, qB, tb + CHUNK);

    // ---- expand chunk index -> full codebook index, then reduce
    int kk[ROWS];
    #pragma unroll
    for (int r = 0; r < ROWS; ++r) kk[r] = bidx[r] * BLOCK + tid;

    // wave-level lexicographic (dist, idx) butterfly reduction
    #pragma unroll
    for (int r = 0; r < ROWS; ++r) {
        float d = best[r]; int i = kk[r];
        #pragma unroll
        for (int off = 32; off >= 1; off >>= 1) {
            float d2 = __shfl_xor(d, off, 64);
            int   i2 = __shfl_xor(i, off, 64);
            if (d2 < d || (d2 == d && i2 < i)) { d = d2; i = i2; }
        }
        best[r] = d; kk[r] = i;
    }

    int wave = tid >> 6;
    if ((tid & 63) == 0) {
        #pragma unroll
        for (int r = 0; r < ROWS; ++r) {
            sRD[wave * ROWS + r] = best[r];
            sRI[wave * ROWS + r] = kk[r];
        }
    }
    __syncthreads();

    if (tid < ROWS) {
        float d = sRD[tid]; int i = sRI[tid];
        #pragma unroll
        for (int w = 1; w < WAVES; ++w) {
            float d2 = sRD[w * ROWS + tid];
            int   i2 = sRI[w * ROWS + tid];
            if (d2 < d || (d2 == d && i2 < i)) { d = d2; i = i2; }
        }
        out[rowbase + tid] = i;
    }
}

extern "C" void kernel_launch(void* const* d_in, const int* in_sizes, int n_in,
                              void* d_out, int out_size, void* d_ws, size_t ws_size,
                              hipStream_t stream)
{
    const float*  hs = (const float*)d_in[0];    // [1,4,4,48,48]
    const float4* cb = (const float4*)d_in[1];   // [32768,4]
    int* out = (int*)d_out;                      // [9216] int32

    float* e2p = (float*)d_ws;                   // 128 KiB in workspace

    vq_prep<<<NK / 256, 256, 0, stream>>>(cb, e2p);

    dim3 grid(NROWS / ROWS), block(BLOCK);       // 768 blocks = 3/CU exact
    vq_argmin_kernel<<<grid, block, 0, stream>>>(hs, cb, (const float2*)e2p, out);
}

// Round 11
// 119.165 us; speedup vs baseline: 1.1274x; 1.0357x over previous
//
#include <hip/hip_runtime.h>
#include <cfloat>

// Emu3 VQ-VAE vector quantizer argmin (exact-rounding match to numpy ref):
//   x [9216,4] f32 (channels-last gather from [1,4,4,48,48])
//   e [32768,4] f32
//   out[n] = argmin_k fl( fl(x2+e2) - 2*fl(dot) ), first-min tie semantics.
//
// Round 16 — deconfound R15: keep the op-diet, drop setprio:
//  - R15 bundle (e2-dwordx2 + peeled tail + setprio) REGRESSED 73.7->79.2us.
//    Suspect: setprio — all waves share the same phase pattern staggered, so
//    boosting compute-phase waves systematically starves the wave issuing
//    loads (m190 GEMM-negative regime, not the attn-positive one). VGPR
//    64->52 also shows a schedule restructure.
//  - This round: R12 skeleton + paired-permuted e2 (one dwordx2/chunk,
//    bitwise-same values, validated absmax=0 in R15) + peeled tail,
//    NO setprio. Loads/chunk 4->3, -2 addr VALU vs R12.
//  - Distance chain + min3 pair-update bitwise identical to R12.
//  - Pre-commit: if main >= 73.7us, revert to R12 verbatim and declare
//    ROOFLINE (issue-stream ceiling, all levers ablated).

#define ROWS  12
#define BLOCK 512
#define WAVES (BLOCK / 64)
#define NROWS 9216
#define NK    32768
#define EPT   2
#define CHUNK (BLOCK * EPT)   // 1024

__device__ __forceinline__ float rlf(float v) {
    return __builtin_bit_cast(float,
        __builtin_amdgcn_readfirstlane(__builtin_bit_cast(int, v)));
}

__global__ __launch_bounds__(256)
void vq_prep(const float4* __restrict__ cb, float* __restrict__ e2p)
{
    int k = blockIdx.x * 256 + threadIdx.x;   // 32768 threads
    float4 e = cb[k];
    float q = __fadd_rn(__fadd_rn(__fadd_rn(__fmul_rn(e.x, e.x),
                                            __fmul_rn(e.y, e.y)),
                                  __fmul_rn(e.z, e.z)),
                        __fmul_rn(e.w, e.w));
    // Permuted layout: chunk c = k>>10, w = k&1023. Lane t of chunk c reads
    // float2 at (c*512 + t): .x = e2(c*1024+t), .y = e2(c*1024+512+t).
    int c = k >> 10;
    int w = k & 1023;
    int pos = c * 1024 + ((w < 512) ? (2 * w) : (2 * (w - 512) + 1));
    e2p[pos] = q;
}

__global__ __launch_bounds__(BLOCK)
__attribute__((amdgpu_waves_per_eu(3, 4)))
void vq_argmin_kernel(const float* __restrict__ hs,
                      const float4* __restrict__ cb,
                      const float2* __restrict__ e2p2,
                      int* __restrict__ out)
{
    __shared__ float sRD[WAVES * ROWS];
    __shared__ int   sRI[WAVES * ROWS];

    const int tid = threadIdx.x;
    const int rowbase = blockIdx.x * ROWS;

    // Block-uniform x components -> readfirstlane into SGPRs.
    float sx0[ROWS], sx1[ROWS], sx2[ROWS], sx3[ROWS], sq[ROWS];
    float best[ROWS];
    int   bidx[ROWS];   // stores chunk index m; k = m*BLOCK + tid

    #pragma unroll
    for (int r = 0; r < ROWS; ++r) {
        int n = rowbase + r;
        int t = n / 2304;                 // 2304 = 48*48
        int rem = n - t * 2304;
        const float* ptr = hs + t * 9216 + rem;   // + c*2304 per channel
        float a0 = ptr[0], a1 = ptr[2304], a2 = ptr[4608], a3 = ptr[6912];
        float q = __fadd_rn(__fadd_rn(__fadd_rn(__fmul_rn(a0, a0),
                                                __fmul_rn(a1, a1)),
                                      __fmul_rn(a2, a2)),
                            __fmul_rn(a3, a3));
        sx0[r] = rlf(a0); sx1[r] = rlf(a1);
        sx2[r] = rlf(a2); sx3[r] = rlf(a3);
        sq[r]  = rlf(q);
        best[r] = FLT_MAX; bidx[r] = 0;
    }

    float4 eA[EPT], eB[EPT];
    float2 qA, qB;                        // paired e2 for the two entries

    auto load_chunk = [&](float4* e, float2& q, int tb) {
        #pragma unroll
        for (int j = 0; j < EPT; ++j) e[j] = cb[tb + tid + j * BLOCK];
        q = e2p2[(tb >> 10) * 512 + tid];           // one dwordx2
    };
    auto compute_chunk = [&](const float4* e, const float2& q, int tb) {
        float4 ea = e[0], eb = e[1];
        float  qa = q.x, qb = q.y;
        int m1 = tb / BLOCK;              // uniform chunk indices
        int m2 = m1 + 1;
        #pragma unroll
        for (int r = 0; r < ROWS; ++r) {
            float dota = __fmul_rn(sx0[r], ea.x);
            dota = __fmaf_rn(sx1[r], ea.y, dota);
            dota = __fmaf_rn(sx2[r], ea.z, dota);
            dota = __fmaf_rn(sx3[r], ea.w, dota);
            float ta = __fadd_rn(sq[r], qa);
            float da = __fmaf_rn(dota, -2.0f, ta);

            float dotb = __fmul_rn(sx0[r], eb.x);
            dotb = __fmaf_rn(sx1[r], eb.y, dotb);
            dotb = __fmaf_rn(sx2[r], eb.z, dotb);
            dotb = __fmaf_rn(sx3[r], eb.w, dotb);
            float tb2 = __fadd_rn(sq[r], qb);
            float db = __fmaf_rn(dotb, -2.0f, tb2);

            // min3 pair-update: 5 VALU for 2 evals, first-min tie-exact.
            float nb = fminf(fminf(best[r], da), db);   // -> v_min3_f32
            int   w  = (da <= db) ? m1 : m2;            // pair winner (tie->m1)
            if (nb < best[r]) bidx[r] = w;              // strict < keeps earliest
            best[r] = nb;
        }
    };

    // ---- ping-pong K loop, peeled tail (no dummy reload)
    load_chunk(eA, qA, 0);
    int tb = 0;
    for (; tb + 2 * CHUNK < NK; tb += 2 * CHUNK) {    // 15 full iterations
        load_chunk(eB, qB, tb + CHUNK);
        compute_chunk(eA, qA, tb);
        load_chunk(eA, qA, tb + 2 * CHUNK);
        compute_chunk(eB, qB, tb + CHUNK);
    }
    load_chunk(eB, qB, tb + CHUNK);                   // final pair
    compute_chunk(eA, qA, tb);
    compute_chunk(eB, qB, tb + CHUNK);

    // ---- expand chunk index -> full codebook index, then reduce
    int kk[ROWS];
    #pragma unroll
    for (int r = 0; r < ROWS; ++r) kk[r] = bidx[r] * BLOCK + tid;

    // wave-level lexicographic (dist, idx) butterfly reduction
    #pragma unroll
    for (int r = 0; r < ROWS; ++r) {
        float d = best[r]; int i = kk[r];
        #pragma unroll
        for (int off = 32; off >= 1; off >>= 1) {
            float d2 = __shfl_xor(d, off, 64);
            int   i2 = __shfl_xor(i, off, 64);
            if (d2 < d || (d2 == d && i2 < i)) { d = d2; i = i2; }
        }
        best[r] = d; kk[r] = i;
    }

    int wave = tid >> 6;
    if ((tid & 63) == 0) {
        #pragma unroll
        for (int r = 0; r < ROWS; ++r) {
            sRD[wave * ROWS + r] = best[r];
            sRI[wave * ROWS + r] = kk[r];
        }
    }
    __syncthreads();

    if (tid < ROWS) {
        float d = sRD[tid]; int i = sRI[tid];
        #pragma unroll
        for (int w = 1; w < WAVES; ++w) {
            float d2 = sRD[w * ROWS + tid];
            int   i2 = sRI[w * ROWS + tid];
            if (d2 < d || (d2 == d && i2 < i)) { d = d2; i = i2; }
        }
        out[rowbase + tid] = i;
    }
}

extern "C" void kernel_launch(void* const* d_in, const int* in_sizes, int n_in,
                              void* d_out, int out_size, void* d_ws, size_t ws_size,
                              hipStream_t stream)
{
    const float*  hs = (const float*)d_in[0];    // [1,4,4,48,48]
    const float4* cb = (const float4*)d_in[1];   // [32768,4]
    int* out = (int*)d_out;                      // [9216] int32

    float* e2p = (float*)d_ws;                   // 128 KiB in workspace

    vq_prep<<<NK / 256, 256, 0, stream>>>(cb, e2p);

    dim3 grid(NROWS / ROWS), block(BLOCK);       // 768 blocks = 3/CU exact
    vq_argmin_kernel<<<grid, block, 0, stream>>>(hs, cb, (const float2*)e2p, out);
}